// Round 4
// baseline (108.546 us; speedup 1.0000x reference)
//
#include <hip/hip_runtime.h>
#include <hip/hip_bf16.h>
#include <stdint.h>

#define NTOK 4096
#define DIM  256
#define HID  1024
#define NEXP 8
#define MTILE 32
#define HC 64
#define HSLICE 256
#define NSLICE 4

typedef float f32x4 __attribute__((ext_vector_type(4)));
typedef short s16x8 __attribute__((ext_vector_type(8)));

__device__ __forceinline__ unsigned short f2bf(float f) {
  union { float f; unsigned u; } v; v.f = f;
  unsigned r = v.u + 0x7FFFu + ((v.u >> 16) & 1u);
  return (unsigned short)(r >> 16);
}

__device__ __forceinline__ void mfma16(f32x4& acc, s16x8 a, s16x8 b) {
  asm("v_mfma_f32_16x16x32_bf16 %0, %1, %2, %0" : "+v"(acc) : "v"(a), "v"(b));
}
__device__ __forceinline__ void accfence(f32x4& a) {   // MFMA->VALU read hazard
  asm volatile("s_nop 7" : "+v"(a));
}
__device__ __forceinline__ void initfence(f32x4& a) {  // VALU init -> MFMA srcC hazard
  asm volatile("s_nop 1" : "+v"(a));
}

// LDS-only barrier: DS ops may not cross (sched_barrier 0x7F blocks DS/DS_READ/DS_WRITE),
// global loads MAY stay in flight across it (no vmcnt drain, unlike __syncthreads).
__device__ __forceinline__ void lds_barrier() {
  __builtin_amdgcn_sched_barrier(0x7F);
  asm volatile("s_waitcnt lgkmcnt(0)");
  __builtin_amdgcn_s_barrier();
  __builtin_amdgcn_sched_barrier(0x7F);
}

// ---- transpose + f32->bf16 : in [E][R][C] f32 -> out [E][C][R] bf16 ----
__global__ __launch_bounds__(256) void tr_cvt(const float* __restrict__ in,
                                              unsigned short* __restrict__ out,
                                              int R, int C) {
  __shared__ float tile[32][33];
  int e = blockIdx.z;
  int r0 = blockIdx.y * 32, c0 = blockIdx.x * 32;
  int tx = threadIdx.x, ty = threadIdx.y;
  const float* ip = in + (size_t)e * R * C;
  unsigned short* op = out + (size_t)e * R * C;
  #pragma unroll
  for (int k = 0; k < 4; ++k)
    tile[ty + 8*k][tx] = ip[(size_t)(r0 + ty + 8*k) * C + c0 + tx];
  __syncthreads();
  #pragma unroll
  for (int k = 0; k < 4; ++k)
    op[(size_t)(c0 + ty + 8*k) * R + r0 + tx] = f2bf(tile[tx][ty + 8*k]);
}

// ---- gate + top-2 + block-aggregated routing (16 tokens/block, 16 lanes/token) ----
__global__ __launch_bounds__(256) void gate_route(const float* __restrict__ x,
    const float* __restrict__ gW, const float* __restrict__ gb,
    const float* __restrict__ temp,
    int* __restrict__ counts, int* __restrict__ list,
    unsigned short* __restrict__ xbf) {
  __shared__ int pairs[16][2];
  __shared__ int lcnt[NEXP], lbase[NEXP], lrank[NEXP];
  int tid = threadIdx.x;
  int w = tid >> 6, lane = tid & 63;
  int sl = lane & 15, g = lane >> 4;
  if (tid < NEXP) { lcnt[tid] = 0; lrank[tid] = 0; }
  __syncthreads();
  int t0 = blockIdx.x * 16;
  int tok = w * 4 + g;
  int n = t0 + tok;

  float4 xv[4];
  #pragma unroll
  for (int p = 0; p < 4; ++p)
    xv[p] = *reinterpret_cast<const float4*>(x + (size_t)n * DIM + sl * 16 + p * 4);

  {
    s16x8 xb0, xb1;
    xb0[0]=(short)f2bf(xv[0].x); xb0[1]=(short)f2bf(xv[0].y); xb0[2]=(short)f2bf(xv[0].z); xb0[3]=(short)f2bf(xv[0].w);
    xb0[4]=(short)f2bf(xv[1].x); xb0[5]=(short)f2bf(xv[1].y); xb0[6]=(short)f2bf(xv[1].z); xb0[7]=(short)f2bf(xv[1].w);
    xb1[0]=(short)f2bf(xv[2].x); xb1[1]=(short)f2bf(xv[2].y); xb1[2]=(short)f2bf(xv[2].z); xb1[3]=(short)f2bf(xv[2].w);
    xb1[4]=(short)f2bf(xv[3].x); xb1[5]=(short)f2bf(xv[3].y); xb1[6]=(short)f2bf(xv[3].z); xb1[7]=(short)f2bf(xv[3].w);
    *reinterpret_cast<s16x8*>(xbf + (size_t)n * DIM + sl * 16)     = xb0;
    *reinterpret_cast<s16x8*>(xbf + (size_t)n * DIM + sl * 16 + 8) = xb1;
  }

  float acc[NEXP];
  #pragma unroll
  for (int e = 0; e < NEXP; ++e) {
    const float* we = gW + (size_t)e * DIM + sl * 16;
    float a = 0.f;
    #pragma unroll
    for (int p = 0; p < 4; ++p) {
      float4 wv = *reinterpret_cast<const float4*>(we + p * 4);
      a += xv[p].x*wv.x + xv[p].y*wv.y + xv[p].z*wv.z + xv[p].w*wv.w;
    }
    acc[e] = a;
  }
  #pragma unroll
  for (int off = 1; off < 16; off <<= 1) {
    #pragma unroll
    for (int e = 0; e < NEXP; ++e) acc[e] += __shfl_xor(acc[e], off);
  }
  if (sl == 0) {
    float t = temp[0];
    float s[NEXP];
    #pragma unroll
    for (int e = 0; e < NEXP; ++e) s[e] = (acc[e] + gb[e]) / t;
    int b0 = 0; float v0 = s[0];
    #pragma unroll
    for (int e = 1; e < NEXP; ++e) if (s[e] > v0) { v0 = s[e]; b0 = e; }
    int b1i = 0; float v1 = -3.4e38f;
    #pragma unroll
    for (int e = 0; e < NEXP; ++e) if (e != b0 && s[e] > v1) { v1 = s[e]; b1i = e; }
    pairs[tok][0] = b0;
    pairs[tok][1] = b1i;
    atomicAdd(&lcnt[b0], 1);
    atomicAdd(&lcnt[b1i], 1);
  }
  __syncthreads();
  if (tid < NEXP) lbase[tid] = atomicAdd(&counts[tid], lcnt[tid]);
  __syncthreads();
  if (tid < 32) {
    int tk = tid >> 1;
    int e = pairs[tk][tid & 1];
    int r = atomicAdd(&lrank[e], 1);
    list[e * NTOK + lbase[e] + r] = t0 + tk;
  }
}

// ---- fused per-expert FFN: weights direct global->VGPR, X/h in LDS ----
__global__ __launch_bounds__(256, 4) void moe_ffn(
    const unsigned short* __restrict__ xbf,
    const unsigned short* __restrict__ W1T,  // [E][H][D] bf16
    const unsigned short* __restrict__ W2T,  // [E][D][H] bf16
    const float* __restrict__ b1g, const float* __restrict__ b2g,
    const int* __restrict__ counts, const int* __restrict__ list,
    float* __restrict__ out) {
  int b = blockIdx.x;
  int e = b & 7;
  int r = b >> 3;
  int s = r & (NSLICE - 1);
  int t = r >> 2;
  int cnt = counts[e];
  if (t * MTILE >= cnt) return;

  __shared__ __align__(16) short Xs[32][264];
  __shared__ __align__(16) short hs[2][32][72];

  int tid = threadIdx.x;
  int l = tid & 63, w = tid >> 6;
  int lr = l & 15, lg = l >> 4, kg = lg * 8;
  const int* mylist = list + e * NTOK + t * MTILE;

  // stage gathered X tile (32 x 256 bf16)
  #pragma unroll
  for (int p = 0; p < 4; ++p) {
    int c = tid + p * 256;
    int row = c >> 5, col = (c & 31) * 8;
    int grow = t * MTILE + row;
    int ntok = (grow < cnt) ? mylist[row] : 0;
    *(s16x8*)&Xs[row][col] = *(const s16x8*)(xbf + (size_t)ntok * DIM + col);
  }

  f32x4 acc[2][4] = {};
  const unsigned short* W1e = W1T + (size_t)e * HID * DIM;
  const unsigned short* W2e = W2T + (size_t)e * DIM * HID;
  int hbase = s * HSLICE;

  lds_barrier();

  #pragma unroll
  for (int c = 0; c < HSLICE / HC; ++c) {
    int hc = hbase + c * HC;
    // GEMM1: 32 tokens x 64 h-cols (wave w: cols w*16+lr), k = 256
    f32x4 ha[2] = {};
    initfence(ha[0]); initfence(ha[1]);
    const unsigned short* bsrc = W1e + (size_t)(hc + w * 16 + lr) * DIM + kg;
    #pragma unroll
    for (int kb = 0; kb < 8; ++kb) {
      s16x8 bv = *(const s16x8*)(bsrc + kb * 32);
      s16x8 a0 = *(const s16x8*)&Xs[lr][kb * 32 + kg];
      s16x8 a1 = *(const s16x8*)&Xs[16 + lr][kb * 32 + kg];
      mfma16(ha[0], a0, bv);
      mfma16(ha[1], a1, bv);
    }
    accfence(ha[0]); accfence(ha[1]);
    float bb = b1g[e * HID + hc + w * 16 + lr];
    #pragma unroll
    for (int m = 0; m < 2; ++m) {
      #pragma unroll
      for (int q = 0; q < 4; ++q) {
        float hv = fmaxf(ha[m][q] + bb, 0.f);
        hs[c & 1][m * 16 + lg * 4 + q][w * 16 + lr] = (short)f2bf(hv);
      }
    }
    lds_barrier();
    // GEMM2: 32 tokens x 256 d (wave w: cols w*64..), k = 64
    #pragma unroll
    for (int kb = 0; kb < 2; ++kb) {
      s16x8 a0 = *(const s16x8*)&hs[c & 1][lr][kb * 32 + kg];
      s16x8 a1 = *(const s16x8*)&hs[c & 1][16 + lr][kb * 32 + kg];
      #pragma unroll
      for (int n = 0; n < 4; ++n) {
        s16x8 bv = *(const s16x8*)(W2e + (size_t)(w * 64 + n * 16 + lr) * HID + hc + kb * 32 + kg);
        mfma16(acc[0][n], a0, bv);
        mfma16(acc[1][n], a1, bv);
      }
    }
    // no trailing barrier: next chunk writes hs[(c+1)&1]; the next lds_barrier
    // proves all waves finished reading hs[c&1] before it is reused.
  }

  #pragma unroll
  for (int m = 0; m < 2; ++m) {
    #pragma unroll
    for (int n = 0; n < 4; ++n) accfence(acc[m][n]);
  }
  #pragma unroll
  for (int m = 0; m < 2; ++m) {
    #pragma unroll
    for (int q = 0; q < 4; ++q) {
      int lrow = m * 16 + lg * 4 + q;
      int grow = t * MTILE + lrow;
      if (grow < cnt) {
        int ntok = mylist[lrow];
        #pragma unroll
        for (int n = 0; n < 4; ++n) {
          int d = w * 64 + n * 16 + lr;
          float v = acc[m][n][q];
          if (s == 0) v += b2g[e * DIM + d];
          atomicAdd(out + (size_t)ntok * DIM + d, v);
        }
      }
    }
  }
}

extern "C" void kernel_launch(void* const* d_in, const int* in_sizes, int n_in,
                              void* d_out, int out_size, void* d_ws, size_t ws_size,
                              hipStream_t stream) {
  const float* x    = (const float*)d_in[0];
  const float* gW   = (const float*)d_in[1];
  const float* gb   = (const float*)d_in[2];
  const float* W1   = (const float*)d_in[3];
  const float* b1   = (const float*)d_in[4];
  const float* W2   = (const float*)d_in[5];
  const float* b2   = (const float*)d_in[6];
  const float* temp = (const float*)d_in[7];
  float* out = (float*)d_out;

  char* ws = (char*)d_ws;
  int*            counts = (int*)(ws + 0);                      // 256 B
  int*            list   = (int*)(ws + 256);                    // 131072 B
  unsigned short* xbf    = (unsigned short*)(ws + 131584);      // 2 MB
  unsigned short* W1T    = (unsigned short*)(ws + 2228736);     // 4 MB
  unsigned short* W2T    = (unsigned short*)(ws + 6423040);     // 4 MB

  hipMemsetAsync(counts, 0, 256, stream);
  hipMemsetAsync(d_out, 0, (size_t)out_size * sizeof(float), stream);

  tr_cvt<<<dim3(HID/32, DIM/32, NEXP), dim3(32, 8, 1), 0, stream>>>(W1, W1T, DIM, HID);
  tr_cvt<<<dim3(DIM/32, HID/32, NEXP), dim3(32, 8, 1), 0, stream>>>(W2, W2T, HID, DIM);
  gate_route<<<NTOK/16, 256, 0, stream>>>(x, gW, gb, temp, counts, list, xbf);
  moe_ffn<<<NEXP * (NTOK/MTILE) * NSLICE, 256, 0, stream>>>(xbf, W1T, W2T, b1, b2, counts, list, out);
}

// Round 5
// 74.865 us; speedup vs baseline: 1.4499x; 1.4499x over previous
//
#include <hip/hip_runtime.h>
#include <hip/hip_bf16.h>
#include <stdint.h>

#define NTOK 4096
#define DIM  256
#define HID  1024
#define NEXP 8
#define MTILE 64
#define HC 32
#define NCHUNK (HID / HC)

typedef float f32x4 __attribute__((ext_vector_type(4)));
typedef short s16x8 __attribute__((ext_vector_type(8)));

__device__ __forceinline__ unsigned short f2bf(float f) {
  union { float f; unsigned u; } v; v.f = f;
  unsigned r = v.u + 0x7FFFu + ((v.u >> 16) & 1u);
  return (unsigned short)(r >> 16);
}

__device__ __forceinline__ void mfma16(f32x4& acc, s16x8 a, s16x8 b) {
  asm("v_mfma_f32_16x16x32_bf16 %0, %1, %2, %0" : "+v"(acc) : "v"(a), "v"(b));
}
__device__ __forceinline__ void accfence(f32x4& a) {   // MFMA->VALU read hazard
  asm volatile("s_nop 7" : "+v"(a));
}
__device__ __forceinline__ void initfence(f32x4& a) {  // VALU init -> MFMA srcC hazard
  asm volatile("s_nop 1" : "+v"(a));
}

// ---- transpose + f32->bf16 + bank-conflict pre-swizzle ----
// mode 1 (W1T [H][D]): col' = col ^ ((row&7)<<3)                (512B rows)
// mode 2 (W2T [D][H]): col' = (col&~31) | ((col&31)^((row&3)<<3)) (64B chunk rows)
__global__ __launch_bounds__(256) void tr_cvt(const float* __restrict__ in,
                                              unsigned short* __restrict__ out,
                                              int R, int C, int mode) {
  __shared__ float tile[32][33];
  int e = blockIdx.z;
  int r0 = blockIdx.y * 32, c0 = blockIdx.x * 32;
  int tx = threadIdx.x, ty = threadIdx.y;
  const float* ip = in + (size_t)e * R * C;
  unsigned short* op = out + (size_t)e * R * C;
  #pragma unroll
  for (int k = 0; k < 4; ++k)
    tile[ty + 8*k][tx] = ip[(size_t)(r0 + ty + 8*k) * C + c0 + tx];
  __syncthreads();
  #pragma unroll
  for (int k = 0; k < 4; ++k) {
    int row = c0 + ty + 8*k;
    int col = r0 + tx;
    int scol = (mode == 1) ? (col ^ ((row & 7) << 3))
                           : ((col & ~31) | ((col & 31) ^ ((row & 3) << 3)));
    op[(size_t)row * R + scol] = f2bf(tile[tx][ty + 8*k]);
  }
}

// ---- gate + top-2 + block-aggregated routing (16 tokens/block) ----
// list entries encode token*2 + slot  (slot 0 = top1 expert, 1 = top2)
__global__ __launch_bounds__(256) void gate_route(const float* __restrict__ x,
    const float* __restrict__ gW, const float* __restrict__ gb,
    const float* __restrict__ temp,
    int* __restrict__ counts, int* __restrict__ list,
    unsigned short* __restrict__ xbf) {
  __shared__ int pairs[16][2];
  __shared__ int lcnt[NEXP], lbase[NEXP], lrank[NEXP];
  int tid = threadIdx.x;
  int w = tid >> 6, lane = tid & 63;
  int sl = lane & 15, g = lane >> 4;
  if (tid < NEXP) { lcnt[tid] = 0; lrank[tid] = 0; }
  __syncthreads();
  int t0 = blockIdx.x * 16;
  int tok = w * 4 + g;
  int n = t0 + tok;

  float4 xv[4];
  #pragma unroll
  for (int p = 0; p < 4; ++p)
    xv[p] = *reinterpret_cast<const float4*>(x + (size_t)n * DIM + sl * 16 + p * 4);

  {
    s16x8 xb0, xb1;
    xb0[0]=(short)f2bf(xv[0].x); xb0[1]=(short)f2bf(xv[0].y); xb0[2]=(short)f2bf(xv[0].z); xb0[3]=(short)f2bf(xv[0].w);
    xb0[4]=(short)f2bf(xv[1].x); xb0[5]=(short)f2bf(xv[1].y); xb0[6]=(short)f2bf(xv[1].z); xb0[7]=(short)f2bf(xv[1].w);
    xb1[0]=(short)f2bf(xv[2].x); xb1[1]=(short)f2bf(xv[2].y); xb1[2]=(short)f2bf(xv[2].z); xb1[3]=(short)f2bf(xv[2].w);
    xb1[4]=(short)f2bf(xv[3].x); xb1[5]=(short)f2bf(xv[3].y); xb1[6]=(short)f2bf(xv[3].z); xb1[7]=(short)f2bf(xv[3].w);
    *reinterpret_cast<s16x8*>(xbf + (size_t)n * DIM + sl * 16)     = xb0;
    *reinterpret_cast<s16x8*>(xbf + (size_t)n * DIM + sl * 16 + 8) = xb1;
  }

  float acc[NEXP];
  #pragma unroll
  for (int e = 0; e < NEXP; ++e) {
    const float* we = gW + (size_t)e * DIM + sl * 16;
    float a = 0.f;
    #pragma unroll
    for (int p = 0; p < 4; ++p) {
      float4 wv = *reinterpret_cast<const float4*>(we + p * 4);
      a += xv[p].x*wv.x + xv[p].y*wv.y + xv[p].z*wv.z + xv[p].w*wv.w;
    }
    acc[e] = a;
  }
  #pragma unroll
  for (int off = 1; off < 16; off <<= 1) {
    #pragma unroll
    for (int e = 0; e < NEXP; ++e) acc[e] += __shfl_xor(acc[e], off);
  }
  if (sl == 0) {
    float t = temp[0];
    float s[NEXP];
    #pragma unroll
    for (int e = 0; e < NEXP; ++e) s[e] = (acc[e] + gb[e]) / t;
    int b0 = 0; float v0 = s[0];
    #pragma unroll
    for (int e = 1; e < NEXP; ++e) if (s[e] > v0) { v0 = s[e]; b0 = e; }
    int b1i = 0; float v1 = -3.4e38f;
    #pragma unroll
    for (int e = 0; e < NEXP; ++e) if (e != b0 && s[e] > v1) { v1 = s[e]; b1i = e; }
    pairs[tok][0] = b0;
    pairs[tok][1] = b1i;
    atomicAdd(&lcnt[b0], 1);
    atomicAdd(&lcnt[b1i], 1);
  }
  __syncthreads();
  if (tid < NEXP) lbase[tid] = atomicAdd(&counts[tid], lcnt[tid]);
  __syncthreads();
  if (tid < 32) {
    int tk = tid >> 1;
    int e = pairs[tk][tid & 1];
    int r = atomicAdd(&lrank[e], 1);
    list[e * NTOK + lbase[e] + r] = (t0 + tk) * 2 + (tid & 1);
  }
}

// ---- fused per-expert FFN, full H per block, LDS dbuf weights via global_load_lds ----
__global__ __launch_bounds__(512, 2) void moe_ffn(
    const unsigned short* __restrict__ xbf,
    const unsigned short* __restrict__ W1T,  // [E][H][D] bf16, row-swizzled mode1
    const unsigned short* __restrict__ W2T,  // [E][D][H] bf16, row-swizzled mode2
    const float* __restrict__ b1g, const float* __restrict__ b2g,
    const int* __restrict__ counts, const int* __restrict__ list,
    float* __restrict__ ybuf) {
  int b = blockIdx.x;
  int e = b & 7;
  int t = b >> 3;
  int cnt = counts[e];
  if (t * MTILE >= cnt) return;

  __shared__ __align__(16) short Xs[64 * 256];        // swizzled ^((row&7)<<3)
  __shared__ __align__(16) short W1b[2][HC * 256];    // linear image of swizzled global
  __shared__ __align__(16) short W2b[2][256 * HC];    // linear image of swizzled global
  __shared__ __align__(16) short hsb[2][64 * 56];     // padded, stride 56
  __shared__ float b1s[HID];

  int tid = threadIdx.x;
  int l = tid & 63, w = tid >> 6;
  int lr = l & 15, lg = l >> 4, kg = lg * 8;
  int wm = w & 3, wn = w >> 2;        // GEMM1 frag: rows wm*16, h-col wn*16
  int wr = w & 1, wc = w >> 1;        // GEMM2: rows wr*32, cols wc*64
  const int* mylist = list + e * NTOK + t * MTILE;
  const unsigned short* W1e = W1T + (size_t)e * HID * DIM;
  const unsigned short* W2e = W2T + (size_t)e * DIM * HID;

  // ---- stage helpers (wave-uniform LDS base + lane*16; per-lane global src) ----
  auto stage = [&](int hc, int buf) {
    { // W1 chunk: contiguous 16KB
      const char* src = (const char*)(W1e + (size_t)hc * DIM);
      #pragma unroll
      for (int i = 0; i < 2; ++i) {
        int off = w * 2048 + i * 1024;
        __builtin_amdgcn_global_load_lds(
          (const __attribute__((address_space(1))) void*)(src + off + l * 16),
          (__attribute__((address_space(3))) void*)((char*)&W1b[buf][0] + off), 16, 0, 0);
      }
    }
    { // W2 chunk: gather 32-col slices of [D][H]
      #pragma unroll
      for (int i = 0; i < 2; ++i) {
        int off = w * 2048 + i * 1024;
        int eo = (off >> 1) + l * 8;          // element in chunk image
        int d = eo >> 5, c8 = eo & 31;
        __builtin_amdgcn_global_load_lds(
          (const __attribute__((address_space(1))) void*)(W2e + (size_t)d * HID + hc + c8),
          (__attribute__((address_space(3))) void*)((char*)&W2b[buf][0] + off), 16, 0, 0);
      }
    }
  };

  // ---- prologue: stage chunk 0, b1 -> LDS, gather X (swizzled reg->LDS) ----
  stage(0, 0);
  for (int i = tid; i < HID; i += 512) b1s[i] = b1g[e * HID + i];
  {
    int row = tid >> 3, c0 = (tid & 7) * 32;
    int grow = t * MTILE + row;
    int entry = (grow < cnt) ? mylist[row] : mylist[0];
    int ntok = entry >> 1;
    const unsigned short* xsrc = xbf + (size_t)ntok * DIM + c0;
    #pragma unroll
    for (int p = 0; p < 4; ++p) {
      s16x8 v = *(const s16x8*)(xsrc + p * 8);
      *(s16x8*)&Xs[(row << 8) + ((c0 + p * 8) ^ ((row & 7) << 3))] = v;
    }
  }
  asm volatile("s_waitcnt vmcnt(0) lgkmcnt(0)" ::: "memory");
  __builtin_amdgcn_s_barrier();
  __builtin_amdgcn_sched_barrier(0);

  f32x4 acc[2][4] = {};
  int swz1 = (lr & 7) << 3;
  int swz2 = (lr & 3) << 3;
  int arow = (wm * 16 + lr) << 8;
  int brow = (wn * 16 + lr) << 8;

  #pragma unroll 2
  for (int c = 0; c < NCHUNK; ++c) {
    int buf = c & 1;
    if (c + 1 < NCHUNK) stage((c + 1) * HC, buf ^ 1);

    // GEMM1: h(64 x 32) += X(64 x 256) @ W1chunk^T, split-k accumulators
    f32x4 h0 = {}, h1 = {};
    initfence(h0); initfence(h1);
    const short* w1p = &W1b[buf][0];
    #pragma unroll
    for (int kb = 0; kb < 8; ++kb) {
      int kc = (kb * 32 + kg) ^ swz1;
      s16x8 av = *(const s16x8*)&Xs[arow + kc];
      s16x8 bv = *(const s16x8*)&w1p[brow + kc];
      if (kb & 1) mfma16(h1, av, bv); else mfma16(h0, av, bv);
    }
    accfence(h0); accfence(h1);
    h0 += h1;
    float bb = b1s[c * HC + wn * 16 + lr];
    short* hp = &hsb[buf][0];
    #pragma unroll
    for (int q = 0; q < 4; ++q) {
      float hv = fmaxf(h0[q] + bb, 0.f);
      hp[(wm * 16 + lg * 4 + q) * 56 + wn * 16 + lr] = (short)f2bf(hv);
    }
    asm volatile("s_waitcnt lgkmcnt(0)" ::: "memory");
    __builtin_amdgcn_s_barrier();
    __builtin_amdgcn_sched_barrier(0);

    // GEMM2: y(64 x 256) += h(64 x 32) @ W2chunk^T
    {
      s16x8 a0 = *(const s16x8*)&hp[(wr * 32 + lr) * 56 + kg];
      s16x8 a1 = *(const s16x8*)&hp[(wr * 32 + 16 + lr) * 56 + kg];
      const short* w2p = &W2b[buf][0];
      #pragma unroll
      for (int n = 0; n < 4; ++n) {
        s16x8 bv = *(const s16x8*)&w2p[((wc * 64 + n * 16 + lr) << 5) + (kg ^ swz2)];
        mfma16(acc[0][n], a0, bv);
        mfma16(acc[1][n], a1, bv);
      }
    }
    asm volatile("s_waitcnt vmcnt(0)" ::: "memory");
    __builtin_amdgcn_s_barrier();
    __builtin_amdgcn_sched_barrier(0);
  }

  // ---- epilogue: non-atomic store to slot buffer (+b2) ----
  #pragma unroll
  for (int m = 0; m < 2; ++m) {
    #pragma unroll
    for (int n = 0; n < 4; ++n) accfence(acc[m][n]);
  }
  float b2v[4];
  #pragma unroll
  for (int n = 0; n < 4; ++n) b2v[n] = b2g[e * DIM + wc * 64 + n * 16 + lr];
  #pragma unroll
  for (int m = 0; m < 2; ++m) {
    #pragma unroll
    for (int q = 0; q < 4; ++q) {
      int lrow = wr * 32 + m * 16 + lg * 4 + q;
      int grow = t * MTILE + lrow;
      if (grow < cnt) {
        int entry = mylist[lrow];
        float* yrow = ybuf + (size_t)entry * DIM + wc * 64 + lr;
        #pragma unroll
        for (int n = 0; n < 4; ++n)
          yrow[n * 16] = acc[m][n][q] + b2v[n];
      }
    }
  }
}

// ---- out[n] = ybuf[2n] + ybuf[2n+1] ----
__global__ __launch_bounds__(256) void reduce2(const float* __restrict__ ybuf,
                                               float* __restrict__ out) {
  int i = (blockIdx.x * 256 + threadIdx.x) * 4;
  int n = i >> 8, d = i & 255;
  f32x4 a = *(const f32x4*)(ybuf + ((size_t)n << 9) + d);
  f32x4 b = *(const f32x4*)(ybuf + ((size_t)n << 9) + 256 + d);
  *(f32x4*)(out + i) = a + b;
}

extern "C" void kernel_launch(void* const* d_in, const int* in_sizes, int n_in,
                              void* d_out, int out_size, void* d_ws, size_t ws_size,
                              hipStream_t stream) {
  const float* x    = (const float*)d_in[0];
  const float* gW   = (const float*)d_in[1];
  const float* gb   = (const float*)d_in[2];
  const float* W1   = (const float*)d_in[3];
  const float* b1   = (const float*)d_in[4];
  const float* W2   = (const float*)d_in[5];
  const float* b2   = (const float*)d_in[6];
  const float* temp = (const float*)d_in[7];
  float* out = (float*)d_out;

  char* ws = (char*)d_ws;
  int*            counts = (int*)(ws + 0);                      // 256 B
  int*            list   = (int*)(ws + 256);                    // 128 KB
  unsigned short* xbf    = (unsigned short*)(ws + 131584);      // 2 MB
  unsigned short* W1T    = (unsigned short*)(ws + 2228736);     // 4 MB
  unsigned short* W2T    = (unsigned short*)(ws + 6423040);     // 4 MB
  float*          ybuf   = (float*)(ws + 10617344);             // 8 MB (end ~18.1 MB)

  hipMemsetAsync(counts, 0, 256, stream);

  tr_cvt<<<dim3(HID/32, DIM/32, NEXP), dim3(32, 8, 1), 0, stream>>>(W1, W1T, DIM, HID, 1);
  tr_cvt<<<dim3(DIM/32, HID/32, NEXP), dim3(32, 8, 1), 0, stream>>>(W2, W2T, HID, DIM, 2);
  gate_route<<<NTOK/16, 256, 0, stream>>>(x, gW, gb, temp, counts, list, xbf);
  moe_ffn<<<NEXP * (NTOK/MTILE), 512, 0, stream>>>(xbf, W1T, W2T, b1, b2, counts, list, ybuf);
  reduce2<<<NTOK*DIM/1024, 256, 0, stream>>>(ybuf, out);
}

// Round 6
// 70.759 us; speedup vs baseline: 1.5340x; 1.0580x over previous
//
#include <hip/hip_runtime.h>
#include <hip/hip_bf16.h>
#include <stdint.h>

#define NTOK 4096
#define DIM  256
#define HID  1024
#define NEXP 8
#define MTILE 64
#define HC 64
#define HSLICE 512
#define NSLICE 2
#define NCHUNK (HSLICE / HC)

typedef float f32x4 __attribute__((ext_vector_type(4)));
typedef short s16x8 __attribute__((ext_vector_type(8)));

__device__ __forceinline__ unsigned short f2bf(float f) {
  union { float f; unsigned u; } v; v.f = f;
  unsigned r = v.u + 0x7FFFu + ((v.u >> 16) & 1u);
  return (unsigned short)(r >> 16);
}
__device__ __forceinline__ float bf2f(unsigned short s) {
  union { float f; unsigned u; } v; v.u = ((unsigned)s) << 16;
  return v.f;
}

__device__ __forceinline__ void mfma16(f32x4& acc, s16x8 a, s16x8 b) {
  asm("v_mfma_f32_16x16x32_bf16 %0, %1, %2, %0" : "+v"(acc) : "v"(a), "v"(b));
}
__device__ __forceinline__ void accfence(f32x4& a) {   // MFMA->VALU read hazard
  asm volatile("s_nop 7" : "+v"(a));
}
__device__ __forceinline__ void initfence(f32x4& a) {  // VALU init -> MFMA srcC hazard
  asm volatile("s_nop 1" : "+v"(a));
}

// ---- transpose + f32->bf16 + bank-conflict pre-swizzle ----
// mode 1 (W1T [H][D], 512B rows): col' = col ^ ((row&7)<<3)
// mode 2 (W2T [D][H], 128B chunk rows): 16B slot within each 64-elem group XORed with row&7
__global__ __launch_bounds__(256) void tr_cvt(const float* __restrict__ in,
                                              unsigned short* __restrict__ out,
                                              int R, int C, int mode) {
  __shared__ float tile[32][33];
  int e = blockIdx.z;
  int r0 = blockIdx.y * 32, c0 = blockIdx.x * 32;
  int tx = threadIdx.x, ty = threadIdx.y;
  const float* ip = in + (size_t)e * R * C;
  unsigned short* op = out + (size_t)e * R * C;
  #pragma unroll
  for (int k = 0; k < 4; ++k)
    tile[ty + 8*k][tx] = ip[(size_t)(r0 + ty + 8*k) * C + c0 + tx];
  __syncthreads();
  #pragma unroll
  for (int k = 0; k < 4; ++k) {
    int row = c0 + ty + 8*k;
    int col = r0 + tx;
    int scol = (mode == 1) ? (col ^ ((row & 7) << 3))
                           : ((col & ~63) | ((((col >> 3) & 7) ^ (row & 7)) << 3) | (col & 7));
    op[(size_t)row * R + scol] = f2bf(tile[tx][ty + 8*k]);
  }
}

// ---- gate + top-2 + block-aggregated routing (64 tokens/block) ----
// list entries encode token*2 + slot
__global__ __launch_bounds__(256) void gate_route(const float* __restrict__ x,
    const float* __restrict__ gW, const float* __restrict__ gb,
    const float* __restrict__ temp,
    int* __restrict__ counts, int* __restrict__ list,
    unsigned short* __restrict__ xbf) {
  __shared__ int pairs[64][2];
  __shared__ int lcnt[NEXP], lbase[NEXP], lrank[NEXP];
  int tid = threadIdx.x;
  int w = tid >> 6, lane = tid & 63;
  int sl = lane & 15, g = lane >> 4;
  if (tid < NEXP) { lcnt[tid] = 0; lrank[tid] = 0; }
  __syncthreads();
  int t0 = blockIdx.x * 64;

  for (int it = 0; it < 4; ++it) {
    int tok = it * 16 + w * 4 + g;
    int n = t0 + tok;

    float4 xv[4];
    #pragma unroll
    for (int p = 0; p < 4; ++p)
      xv[p] = *reinterpret_cast<const float4*>(x + (size_t)n * DIM + sl * 16 + p * 4);

    {
      s16x8 xb0, xb1;
      xb0[0]=(short)f2bf(xv[0].x); xb0[1]=(short)f2bf(xv[0].y); xb0[2]=(short)f2bf(xv[0].z); xb0[3]=(short)f2bf(xv[0].w);
      xb0[4]=(short)f2bf(xv[1].x); xb0[5]=(short)f2bf(xv[1].y); xb0[6]=(short)f2bf(xv[1].z); xb0[7]=(short)f2bf(xv[1].w);
      xb1[0]=(short)f2bf(xv[2].x); xb1[1]=(short)f2bf(xv[2].y); xb1[2]=(short)f2bf(xv[2].z); xb1[3]=(short)f2bf(xv[2].w);
      xb1[4]=(short)f2bf(xv[3].x); xb1[5]=(short)f2bf(xv[3].y); xb1[6]=(short)f2bf(xv[3].z); xb1[7]=(short)f2bf(xv[3].w);
      *reinterpret_cast<s16x8*>(xbf + (size_t)n * DIM + sl * 16)     = xb0;
      *reinterpret_cast<s16x8*>(xbf + (size_t)n * DIM + sl * 16 + 8) = xb1;
    }

    float acc[NEXP];
    #pragma unroll
    for (int e = 0; e < NEXP; ++e) {
      const float* we = gW + (size_t)e * DIM + sl * 16;
      float a = 0.f;
      #pragma unroll
      for (int p = 0; p < 4; ++p) {
        float4 wv = *reinterpret_cast<const float4*>(we + p * 4);
        a += xv[p].x*wv.x + xv[p].y*wv.y + xv[p].z*wv.z + xv[p].w*wv.w;
      }
      acc[e] = a;
    }
    #pragma unroll
    for (int off = 1; off < 16; off <<= 1) {
      #pragma unroll
      for (int e = 0; e < NEXP; ++e) acc[e] += __shfl_xor(acc[e], off);
    }
    if (sl == 0) {
      float t = temp[0];
      float s[NEXP];
      #pragma unroll
      for (int e = 0; e < NEXP; ++e) s[e] = (acc[e] + gb[e]) / t;
      int b0 = 0; float v0 = s[0];
      #pragma unroll
      for (int e = 1; e < NEXP; ++e) if (s[e] > v0) { v0 = s[e]; b0 = e; }
      int b1i = 0; float v1 = -3.4e38f;
      #pragma unroll
      for (int e = 0; e < NEXP; ++e) if (e != b0 && s[e] > v1) { v1 = s[e]; b1i = e; }
      pairs[tok][0] = b0;
      pairs[tok][1] = b1i;
      atomicAdd(&lcnt[b0], 1);
      atomicAdd(&lcnt[b1i], 1);
    }
  }
  __syncthreads();
  if (tid < NEXP) lbase[tid] = atomicAdd(&counts[tid], lcnt[tid]);
  __syncthreads();
  if (tid < 128) {
    int tk = tid >> 1;
    int e = pairs[tk][tid & 1];
    int r = atomicAdd(&lrank[e], 1);
    list[e * NTOK + lbase[e] + r] = (t0 + tk) * 2 + (tid & 1);
  }
}

// ---- fused per-expert FFN: X frags in VGPRs, weights dbuf-LDS via global_load_lds ----
// H split in NSLICE slices; partial y stored bf16 to slot buffer (no atomics).
__global__ __launch_bounds__(512, 2) void moe_ffn(
    const unsigned short* __restrict__ xbf,
    const unsigned short* __restrict__ W1T,  // [E][H][D] bf16, pre-swizzled mode1
    const unsigned short* __restrict__ W2T,  // [E][D][H] bf16, pre-swizzled mode2
    const float* __restrict__ b1g, const float* __restrict__ b2g,
    const int* __restrict__ counts, const int* __restrict__ list,
    unsigned short* __restrict__ ybuf) {
  int b = blockIdx.x;
  int e = b & 7;
  int r = b >> 3;
  int s = r & (NSLICE - 1);
  int t = r >> 1;
  int cnt = counts[e];
  if (t * MTILE >= cnt) return;

  __shared__ __align__(16) short W1b[2][HC * 256];   // 64 KB
  __shared__ __align__(16) short W2b[2][256 * HC];   // 64 KB
  __shared__ __align__(16) short hs[64][72];         // 9 KB
  __shared__ float b1s[HSLICE];                      // 2 KB

  int tid = threadIdx.x;
  int l = tid & 63, w = tid >> 6;
  int lr = l & 15, lg = l >> 4, kg = lg * 8;
  int wm1 = w & 1, wn1 = w >> 1;   // GEMM1: tok-half, hcol 16-group (0..3)
  int wr = w & 1, wc = w >> 1;     // GEMM2: tok-half, d 64-group (0..3)
  int hbase = s * HSLICE;
  const int* mylist = list + e * NTOK + t * MTILE;
  const unsigned short* W1e = W1T + (size_t)e * HID * DIM;
  const unsigned short* W2e = W2T + (size_t)e * DIM * HID;

  auto stage = [&](int hc, int buf) {
    const char* src1 = (const char*)(W1e + (size_t)hc * DIM);
    char* dst1 = (char*)&W1b[buf][0];
    #pragma unroll
    for (int i = 0; i < 4; ++i) {
      int off = w * 4096 + i * 1024;
      __builtin_amdgcn_global_load_lds(
        (const __attribute__((address_space(1))) void*)(src1 + off + l * 16),
        (__attribute__((address_space(3))) void*)(dst1 + off), 16, 0, 0);
    }
    char* dst2 = (char*)&W2b[buf][0];
    #pragma unroll
    for (int i = 0; i < 4; ++i) {
      int off = w * 4096 + i * 1024;
      int eo = (off >> 1) + l * 8;
      int d = eo >> 6, c8 = eo & 63;
      __builtin_amdgcn_global_load_lds(
        (const __attribute__((address_space(1))) void*)(W2e + (size_t)d * HID + hc + c8),
        (__attribute__((address_space(3))) void*)(dst2 + off), 16, 0, 0);
    }
  };

  // ---- prologue: stage chunk 0; b1 slice; X fragments -> VGPR ----
  stage(hbase, 0);
  for (int i = tid; i < HSLICE; i += 512) b1s[i] = b1g[e * HID + hbase + i];

  s16x8 xa[2][8];
  #pragma unroll
  for (int mf = 0; mf < 2; ++mf) {
    int row = wm1 * 32 + mf * 16 + lr;
    int grow = t * MTILE + row;
    int entry = (grow < cnt) ? mylist[row] : mylist[0];
    const unsigned short* xsrc = xbf + (size_t)(entry >> 1) * DIM;
    #pragma unroll
    for (int kb = 0; kb < 8; ++kb)
      xa[mf][kb] = *(const s16x8*)(xsrc + kb * 32 + kg);
  }

  f32x4 acc[2][4] = {};
  #pragma unroll
  for (int m = 0; m < 2; ++m) { initfence(acc[m][0]); initfence(acc[m][1]); initfence(acc[m][2]); initfence(acc[m][3]); }

  asm volatile("s_waitcnt vmcnt(0) lgkmcnt(0)" ::: "memory");
  __builtin_amdgcn_s_barrier();
  __builtin_amdgcn_sched_barrier(0);

  int swz = (lr & 7) << 3;
  int brow1 = (wn1 * 16 + lr) << 8;   // W1b row base (256 elems/row)

  #pragma unroll 2
  for (int c = 0; c < NCHUNK; ++c) {
    int buf = c & 1;
    if (c + 1 < NCHUNK) stage(hbase + (c + 1) * HC, buf ^ 1);

    // GEMM1: h(64 x 64) = X(64 x 256) @ W1chunk^T ; A from regs, B from LDS
    f32x4 ha[2][2] = {};
    initfence(ha[0][0]); initfence(ha[0][1]); initfence(ha[1][0]); initfence(ha[1][1]);
    const short* w1p = &W1b[buf][0];
    #pragma unroll
    for (int kb = 0; kb < 8; ++kb) {
      s16x8 bv = *(const s16x8*)&w1p[brow1 + ((kb * 32 + kg) ^ swz)];
      mfma16(ha[0][kb & 1], xa[0][kb], bv);
      mfma16(ha[1][kb & 1], xa[1][kb], bv);
    }
    accfence(ha[0][0]); accfence(ha[0][1]); accfence(ha[1][0]); accfence(ha[1][1]);
    float bb = b1s[c * HC + wn1 * 16 + lr];
    #pragma unroll
    for (int mf = 0; mf < 2; ++mf) {
      f32x4 h = ha[mf][0] + ha[mf][1];
      #pragma unroll
      for (int q = 0; q < 4; ++q) {
        float hv = fmaxf(h[q] + bb, 0.f);
        hs[wm1 * 32 + mf * 16 + lg * 4 + q][wn1 * 16 + lr] = (short)f2bf(hv);
      }
    }
    asm volatile("s_waitcnt lgkmcnt(0)" ::: "memory");
    __builtin_amdgcn_s_barrier();
    __builtin_amdgcn_sched_barrier(0);

    // GEMM2: y(64 x 256) += h(64 x 64) @ W2chunk^T
    const short* w2p = &W2b[buf][0];
    #pragma unroll
    for (int kb = 0; kb < 2; ++kb) {
      s16x8 a0 = *(const s16x8*)&hs[wr * 32 + lr][kb * 32 + kg];
      s16x8 a1 = *(const s16x8*)&hs[wr * 32 + 16 + lr][kb * 32 + kg];
      #pragma unroll
      for (int n = 0; n < 4; ++n) {
        int d = wc * 64 + n * 16 + lr;
        s16x8 bv = *(const s16x8*)&w2p[(d << 6) + ((kb * 32 + kg) ^ swz)];
        mfma16(acc[0][n], a0, bv);
        mfma16(acc[1][n], a1, bv);
      }
    }
    asm volatile("s_waitcnt vmcnt(0) lgkmcnt(0)" ::: "memory");
    __builtin_amdgcn_s_barrier();
    __builtin_amdgcn_sched_barrier(0);
  }

  // ---- epilogue: bf16 partial store to slot buffer (+b2 from slice 0) ----
  #pragma unroll
  for (int m = 0; m < 2; ++m) {
    #pragma unroll
    for (int n = 0; n < 4; ++n) accfence(acc[m][n]);
  }
  float b2v[4];
  #pragma unroll
  for (int n = 0; n < 4; ++n) b2v[n] = (s == 0) ? b2g[e * DIM + wc * 64 + n * 16 + lr] : 0.f;
  #pragma unroll
  for (int mf = 0; mf < 2; ++mf) {
    #pragma unroll
    for (int q = 0; q < 4; ++q) {
      int lrow = wr * 32 + mf * 16 + lg * 4 + q;
      int grow = t * MTILE + lrow;
      if (grow < cnt) {
        int entry = mylist[lrow];
        unsigned short* yrow = ybuf + ((size_t)entry * NSLICE + s) * DIM + wc * 64 + lr;
        #pragma unroll
        for (int n = 0; n < 4; ++n)
          yrow[n * 16] = f2bf(acc[mf][n][q] + b2v[n]);
      }
    }
  }
}

// ---- out[n][d] = sum over 4 slot-rows of bf16 ybuf ----
__global__ __launch_bounds__(256) void reduce4(const unsigned short* __restrict__ yb,
                                               float* __restrict__ out) {
  int i = (blockIdx.x * 256 + threadIdx.x) * 8;
  int n = i >> 8, d = i & 255;
  const unsigned short* base = yb + ((size_t)n * 4) * DIM + d;
  float sum[8] = {0,0,0,0,0,0,0,0};
  #pragma unroll
  for (int r = 0; r < 4; ++r) {
    s16x8 v = *(const s16x8*)(base + r * DIM);
    #pragma unroll
    for (int j = 0; j < 8; ++j) sum[j] += bf2f((unsigned short)v[j]);
  }
  float4 o0 = {sum[0], sum[1], sum[2], sum[3]};
  float4 o1 = {sum[4], sum[5], sum[6], sum[7]};
  *(float4*)(out + i) = o0;
  *(float4*)(out + i + 4) = o1;
}

extern "C" void kernel_launch(void* const* d_in, const int* in_sizes, int n_in,
                              void* d_out, int out_size, void* d_ws, size_t ws_size,
                              hipStream_t stream) {
  const float* x    = (const float*)d_in[0];
  const float* gW   = (const float*)d_in[1];
  const float* gb   = (const float*)d_in[2];
  const float* W1   = (const float*)d_in[3];
  const float* b1   = (const float*)d_in[4];
  const float* W2   = (const float*)d_in[5];
  const float* b2   = (const float*)d_in[6];
  const float* temp = (const float*)d_in[7];
  float* out = (float*)d_out;

  char* ws = (char*)d_ws;
  int*            counts = (int*)(ws + 0);                      // 256 B
  int*            list   = (int*)(ws + 256);                    // 128 KB
  unsigned short* xbf    = (unsigned short*)(ws + 131584);      // 2 MB
  unsigned short* W1T    = (unsigned short*)(ws + 2228736);     // 4 MB
  unsigned short* W2T    = (unsigned short*)(ws + 6423040);     // 4 MB
  unsigned short* ybuf   = (unsigned short*)(ws + 10617344);    // 8 MB bf16 (end ~18.1 MB)

  hipMemsetAsync(counts, 0, 256, stream);

  tr_cvt<<<dim3(HID/32, DIM/32, NEXP), dim3(32, 8, 1), 0, stream>>>(W1, W1T, DIM, HID, 1);
  tr_cvt<<<dim3(DIM/32, HID/32, NEXP), dim3(32, 8, 1), 0, stream>>>(W2, W2T, HID, DIM, 2);
  gate_route<<<NTOK/64, 256, 0, stream>>>(x, gW, gb, temp, counts, list, xbf);
  moe_ffn<<<NEXP * (NTOK/MTILE) * NSLICE, 512, 0, stream>>>(xbf, W1T, W2T, b1, b2, counts, list, ybuf);
  reduce4<<<NTOK*DIM/2048, 256, 0, stream>>>(ybuf, out);
}